// Round 17
// baseline (4652.633 us; speedup 1.0000x reference)
//
#include <hip/hip_runtime.h>

#define T_STEPS 8192
#define BATCH   128
#define HID     128
#define NTHR    256               // 4 waves, 1/SIMD

typedef float v2f __attribute__((ext_vector_type(2)));

// tanh(z) = 1 - 2/(1+e^{2z}) -- 5 instrs, NaN-free at both infinities.
__device__ __forceinline__ float fast_tanh(float z) {
    float e = __expf(2.0f * z);
    float r = __builtin_amdgcn_rcpf(1.0f + e);
    return fmaf(-2.0f, r, 1.0f);
}

// sum the 2 lanes of a pair; both lanes get the result.
__device__ __forceinline__ float pair_sum(float x) {
    int t1 = __builtin_amdgcn_update_dpp(0, __builtin_bit_cast(int, x),
                                         0xB1 /*quad_perm [1,0,3,2]*/,
                                         0xf, 0xf, false);
    return x + __builtin_bit_cast(float, t1);
}

// wave sum of PAIR-UNIFORM values -> total in lane 63 (5 DPP adds).
__device__ __forceinline__ float wave_sum_pairuniform_l63(float x) {
#define DPP_ADD(ctrl) do {                                                        \
        int t_ = __builtin_amdgcn_update_dpp(0, __builtin_bit_cast(int, x),       \
                                             (ctrl), 0xf, 0xf, false);            \
        x += __builtin_bit_cast(float, t_); } while (0)
    DPP_ADD(0x112); DPP_ADD(0x114); DPP_ADD(0x118);
    DPP_ADD(0x142); DPP_ADD(0x143);
#undef DPP_ADD
    return x;
}

__device__ __forceinline__ float bcast_lane(float v, int l) {
    int r = __builtin_amdgcn_readlane(__builtin_bit_cast(int, v), l);
    return __builtin_bit_cast(float, r);
}

#define FORALL32(M) M(0) M(1) M(2) M(3) M(4) M(5) M(6) M(7) \
                    M(8) M(9) M(10) M(11) M(12) M(13) M(14) M(15) \
                    M(16) M(17) M(18) M(19) M(20) M(21) M(22) M(23) \
                    M(24) M(25) M(26) M(27) M(28) M(29) M(30) M(31)

// R17 = R16 with the s_barrier RETIRED. Exchange is lock-free: lane 63 of
// each wave writes {value, tag=t} as ONE ds_write_b64 (atomic visibility);
// all waves poll the 4 slots until every tag == t. Safety: a wave writes
// step t only after consuming step t-1, so inter-wave drift <= 1 step; the
// parity-2 ring slot being overwritten (tag t+1, old tag t-1) has already
// been read by ALL waves (they each wrote t, which required reading t-1).
// No barrier => waves drift and pipeline y-independent work (x-prep, h1
// stores) across step boundaries instead of rendezvousing every step.
// R14/R15/R16 (4022/4015/4010 us at VALUBusy 27/27/15.6%) proved the step
// is pure-latency-bound; the barrier is the largest removable term left.
__global__ __launch_bounds__(NTHR, 2) void odenet_scan(
    const float* __restrict__ x,
    const float* __restrict__ W1, const float* __restrict__ b1,
    const float* __restrict__ W2, const float* __restrict__ b2,
    const float* __restrict__ W3, const float* __restrict__ b3,
    float* __restrict__ out) {

    const int b    = blockIdx.x;        // batch element
    const int tid  = threadIdx.x;
    const int w    = tid >> 6;          // wave 0..3
    const int lane = tid & 63;
    const int j    = (w << 5) | (lane >> 1);   // owned output unit
    const int s    = lane & 1;                 // k-chunk [64s, 64s+64)

    __shared__ __align__(16) float h1buf[4][136];   // wave-private h1
    __shared__ __align__(16) int2  dyx[2][4];       // [parity][wave] {val,tag}

    // ---- W2 fragment: rows [64s, 64s+64) of column j, packed as 32 v2f ----
    const float* col = W2 + j;          // column j, row stride HID
    const int kb = s << 6;
#define DECLW(i) v2f wp##i = {col[(kb + 2*(i) + 0) * HID],                        \
                              col[(kb + 2*(i) + 1) * HID]};
    FORALL32(DECLW)
#undef DECLW
#define PINW(i) asm volatile("" : "+v"(wp##i));
    FORALL32(PINW)
#undef PINW

    float w1xa = W1[lane],      w1ya = W1[HID + lane],      b1a = b1[lane];
    float w1xb = W1[lane + 64], w1yb = W1[HID + lane + 64], b1b = b1[lane + 64];
    float b2j = b2[j], w3j = W3[j], b3v = b3[0];
    asm volatile("" : "+v"(w1xa), "+v"(w1ya), "+v"(b1a),
                      "+v"(w1xb), "+v"(w1yb), "+v"(b1b),
                      "+v"(b2j), "+v"(w3j), "+v"(b3v));

    float y    = 0.0f;
    float ybuf = 0.0f;
    if (w == 0 && lane == 0) out[b] = 0.0f;   // y_0 = 0

    // ---- x double-buffer ----
    float xbuf  = x[lane * BATCH + b];
    int   nb    = 64;
    float xnext = x[min(nb + lane, T_STEPS - 1) * BATCH + b];
    float xv = bcast_lane(xbuf, 0);
    float ax = fmaf(xv, w1xa, b1a);
    float bx = fmaf(xv, w1xb, b1b);

    const float4* h4 = (const float4*)&h1buf[w][s * 68];

    for (int t = 0; t < T_STEPS - 1; ++t) {
        const int tm = t & 63;

        // ---- layer 1 (critical path from y: fma+tanh+write only) ----
        float ha = fast_tanh(fmaf(y, w1ya, ax));
        float hb = fast_tanh(fmaf(y, w1yb, bx));
        h1buf[w][lane]      = ha;
        h1buf[w][68 + lane] = hb;

        // ---- layer 2: 16 b128 reads of own chunk + 32 v_pk_fma_f32 ----
        v2f a0 = {0.f, 0.f}, a1 = {0.f, 0.f}, a2 = {0.f, 0.f}, a3 = {0.f, 0.f};
        {
            float4 q;
#define FMAP(qi, WA, WB, AA, AB) q = h4[qi];                                      \
            { v2f lo = {q.x, q.y}, hi = {q.z, q.w};                               \
              AA += WA * lo; AB += WB * hi; }
            FMAP( 0, wp0 , wp1 , a0, a1) FMAP( 1, wp2 , wp3 , a2, a3)
            FMAP( 2, wp4 , wp5 , a0, a1) FMAP( 3, wp6 , wp7 , a2, a3)
            FMAP( 4, wp8 , wp9 , a0, a1) FMAP( 5, wp10, wp11, a2, a3)
            FMAP( 6, wp12, wp13, a0, a1) FMAP( 7, wp14, wp15, a2, a3)
            FMAP( 8, wp16, wp17, a0, a1) FMAP( 9, wp18, wp19, a2, a3)
            FMAP(10, wp20, wp21, a0, a1) FMAP(11, wp22, wp23, a2, a3)
            FMAP(12, wp24, wp25, a0, a1) FMAP(13, wp26, wp27, a2, a3)
            FMAP(14, wp28, wp29, a0, a1) FMAP(15, wp30, wp31, a2, a3)
#undef FMAP
        }
        v2f ap = (a0 + a1) + (a2 + a3);

        // ---- pair combine, tanh, layer-3, wave reduce to lane 63 ----
        float z2  = pair_sum(ap.x + ap.y);
        float h2  = fast_tanh(z2 + b2j);
        float dyw = wave_sum_pairuniform_l63(w3j * h2);

        // ---- publish: ONE b64 write {value, tag} from lane 63 ----
        if (lane == 63)
            dyx[t & 1][w] = make_int2(__builtin_bit_cast(int, dyw), t);

        // ---- next step's x-side prep (y-independent; fills poll wait) ----
        const int tmn = (t + 1) & 63;
        if (tmn == 0) {
            xbuf = xnext;
            nb += 64;
            xnext = x[min(nb + lane, T_STEPS - 1) * BATCH + b];
        }
        float xvn = bcast_lane(xbuf, tmn);
        float axn = fmaf(xvn, w1xa, b1a);
        float bxn = fmaf(xvn, w1xb, b1b);

        // ---- lock-free consume: poll 4 slots until all tags == t ----
        const int2* dp = &dyx[t & 1][0];
        int2 d0, d1, d2, d3;
        do {
            asm volatile("" ::: "memory");   // force re-load each iteration
            d0 = dp[0]; d1 = dp[1]; d2 = dp[2]; d3 = dp[3];
        } while (d0.y != t || d1.y != t || d2.y != t || d3.y != t);

        y += ((__builtin_bit_cast(float, d0.x) + __builtin_bit_cast(float, d1.x))
            + (__builtin_bit_cast(float, d2.x) + __builtin_bit_cast(float, d3.x)))
            + b3v;                                   // DT = 1.0

        ybuf = (lane == tm) ? y : ybuf;
        if (w == 0 && tm == 63)
            out[(t - 62 + lane) * BATCH + b] = ybuf;

        ax = axn; bx = bxn;
    }
    // tail: t=8128..8190 captured y_8129..y_8191 in lanes 0..62
    if (w == 0 && lane < 63)
        out[(T_STEPS - 63 + lane) * BATCH + b] = ybuf;
}

extern "C" void kernel_launch(void* const* d_in, const int* in_sizes, int n_in,
                              void* d_out, int out_size, void* d_ws, size_t ws_size,
                              hipStream_t stream) {
    const float* x  = (const float*)d_in[0];
    const float* W1 = (const float*)d_in[1];
    const float* b1 = (const float*)d_in[2];
    const float* W2 = (const float*)d_in[3];
    const float* b2 = (const float*)d_in[4];
    const float* W3 = (const float*)d_in[5];
    const float* b3 = (const float*)d_in[6];

    odenet_scan<<<dim3(BATCH), dim3(NTHR), 0, stream>>>(
        x, W1, b1, W2, b2, W3, b3, (float*)d_out);
}

// Round 18
// 4032.744 us; speedup vs baseline: 1.1537x; 1.1537x over previous
//
#include <hip/hip_runtime.h>

#define T_STEPS 8192
#define BATCH   128
#define HID     128
#define NTHR    256               // 4 waves, 1/SIMD

typedef float v2f __attribute__((ext_vector_type(2)));

// tanh(z) = 1 - 2/(1+e^{2z}) -- 5 instrs, NaN-free at both infinities.
__device__ __forceinline__ float fast_tanh(float z) {
    float e = __expf(2.0f * z);
    float r = __builtin_amdgcn_rcpf(1.0f + e);
    return fmaf(-2.0f, r, 1.0f);
}

// sum the 2 lanes of a pair; both lanes get the result.
__device__ __forceinline__ float pair_sum(float x) {
    int t1 = __builtin_amdgcn_update_dpp(0, __builtin_bit_cast(int, x),
                                         0xB1 /*quad_perm [1,0,3,2]*/,
                                         0xf, 0xf, false);
    return x + __builtin_bit_cast(float, t1);
}

// wave sum of PAIR-UNIFORM values -> total in lane 63 (5 DPP adds).
__device__ __forceinline__ float wave_sum_pairuniform_l63(float x) {
#define DPP_ADD(ctrl) do {                                                        \
        int t_ = __builtin_amdgcn_update_dpp(0, __builtin_bit_cast(int, x),       \
                                             (ctrl), 0xf, 0xf, false);            \
        x += __builtin_bit_cast(float, t_); } while (0)
    DPP_ADD(0x112); DPP_ADD(0x114); DPP_ADD(0x118);
    DPP_ADD(0x142); DPP_ADD(0x143);
#undef DPP_ADD
    return x;
}

__device__ __forceinline__ float bcast_lane(float v, int l) {
    int r = __builtin_amdgcn_readlane(__builtin_bit_cast(int, v), l);
    return __builtin_bit_cast(float, r);
}

#define FORALL32(M) M(0) M(1) M(2) M(3) M(4) M(5) M(6) M(7) \
                    M(8) M(9) M(10) M(11) M(12) M(13) M(14) M(15) \
                    M(16) M(17) M(18) M(19) M(20) M(21) M(22) M(23) \
                    M(24) M(25) M(26) M(27) M(28) M(29) M(30) M(31)

// R18 = R16 revert (best: 4010 us). R17 proved software polling through the
// LDS pipe is ~16% worse than s_barrier (expected-case poll = one full LDS RT
// after the producer's write; hw barrier releases in lockstep). The ledger
// R8-R17 brackets the floor: dur is insensitive to 2x issue variation,
// barrier count 1 is optimal, both remaining LDS RTs are irreducible under
// the register wall (self-sufficiency needs 256 wt/lane; allocator caps ~148
// and spills serialize -- R7/R12). Step = serial chain: tanh -> h1 LDS RT ->
// 32 pk_fma -> tanh -> DPP reduce -> barrier + dyx LDS RT -> y.
__global__ __launch_bounds__(NTHR, 2) void odenet_scan(
    const float* __restrict__ x,
    const float* __restrict__ W1, const float* __restrict__ b1,
    const float* __restrict__ W2, const float* __restrict__ b2,
    const float* __restrict__ W3, const float* __restrict__ b3,
    float* __restrict__ out) {

    const int b    = blockIdx.x;        // batch element
    const int tid  = threadIdx.x;
    const int w    = tid >> 6;          // wave 0..3
    const int lane = tid & 63;
    const int j    = (w << 5) | (lane >> 1);   // owned output unit
    const int s    = lane & 1;                 // k-chunk [64s, 64s+64)

    // wave-private h1: 2 chunks x 68 floats (64 + 4 pad; chunk 1 16B-aligned,
    // bank-shifted by 4)
    __shared__ __align__(16) float h1buf[4][136];
    __shared__ __align__(16) float dyx[2][4];  // [parity][wave] dy partials

    // ---- W2 fragment: rows [64s, 64s+64) of column j, packed as 32 v2f ----
    const float* col = W2 + j;          // column j, row stride HID
    const int kb = s << 6;
#define DECLW(i) v2f wp##i = {col[(kb + 2*(i) + 0) * HID],                        \
                              col[(kb + 2*(i) + 1) * HID]};
    FORALL32(DECLW)
#undef DECLW
#define PINW(i) asm volatile("" : "+v"(wp##i));
    FORALL32(PINW)
#undef PINW

    // layer-1 weights for the two h1 units this lane computes (k=lane, lane+64)
    float w1xa = W1[lane],      w1ya = W1[HID + lane],      b1a = b1[lane];
    float w1xb = W1[lane + 64], w1yb = W1[HID + lane + 64], b1b = b1[lane + 64];
    float b2j = b2[j], w3j = W3[j], b3v = b3[0];
    asm volatile("" : "+v"(w1xa), "+v"(w1ya), "+v"(b1a),
                      "+v"(w1xb), "+v"(w1yb), "+v"(b1b),
                      "+v"(b2j), "+v"(w3j), "+v"(b3v));

    float y    = 0.0f;
    float ybuf = 0.0f;                  // all waves capture (symmetric arrival)
    if (w == 0 && lane == 0) out[b] = 0.0f;   // y_0 = 0

    // ---- x double-buffer: xbuf = current 64-step block, xnext = next ----
    float xbuf  = x[lane * BATCH + b];                 // block 0
    int   nb    = 64;                                  // next block base
    float xnext = x[min(nb + lane, T_STEPS - 1) * BATCH + b];
    float xv = bcast_lane(xbuf, 0);
    float ax = fmaf(xv, w1xa, b1a);     // x-side of layer 1 for t=0
    float bx = fmaf(xv, w1xb, b1b);

    const float4* h4 = (const float4*)&h1buf[w][s * 68];

    for (int t = 0; t < T_STEPS - 1; ++t) {
        const int tm = t & 63;

        // ---- layer 1 (critical path from y: fma+tanh+write only) ----
        float ha = fast_tanh(fmaf(y, w1ya, ax));
        float hb = fast_tanh(fmaf(y, w1yb, bx));
        h1buf[w][lane]      = ha;       // chunk 0, 2-way bank alias (free)
        h1buf[w][68 + lane] = hb;       // chunk 1

        // ---- layer 2: 16 b128 reads of own chunk + 32 v_pk_fma_f32 ----
        v2f a0 = {0.f, 0.f}, a1 = {0.f, 0.f}, a2 = {0.f, 0.f}, a3 = {0.f, 0.f};
        {
            float4 q;
#define FMAP(qi, WA, WB, AA, AB) q = h4[qi];                                      \
            { v2f lo = {q.x, q.y}, hi = {q.z, q.w};                               \
              AA += WA * lo; AB += WB * hi; }
            FMAP( 0, wp0 , wp1 , a0, a1) FMAP( 1, wp2 , wp3 , a2, a3)
            FMAP( 2, wp4 , wp5 , a0, a1) FMAP( 3, wp6 , wp7 , a2, a3)
            FMAP( 4, wp8 , wp9 , a0, a1) FMAP( 5, wp10, wp11, a2, a3)
            FMAP( 6, wp12, wp13, a0, a1) FMAP( 7, wp14, wp15, a2, a3)
            FMAP( 8, wp16, wp17, a0, a1) FMAP( 9, wp18, wp19, a2, a3)
            FMAP(10, wp20, wp21, a0, a1) FMAP(11, wp22, wp23, a2, a3)
            FMAP(12, wp24, wp25, a0, a1) FMAP(13, wp26, wp27, a2, a3)
            FMAP(14, wp28, wp29, a0, a1) FMAP(15, wp30, wp31, a2, a3)
#undef FMAP
        }
        v2f ap = (a0 + a1) + (a2 + a3);

        // ---- combine k-halves in-pair (1 DPP), tanh, layer-3, wave reduce ----
        float z2  = pair_sum(ap.x + ap.y);           // full dot for unit j
        float h2  = fast_tanh(z2 + b2j);
        float dyw = wave_sum_pairuniform_l63(w3j * h2);
        if (lane == 63) dyx[t & 1][w] = dyw;         // direct from lane 63

        // ---- next step's x-side prep (y-independent; fills barrier wait) ----
        const int tmn = (t + 1) & 63;
        if (tmn == 0) {                              // rotate x blocks
            xbuf = xnext;
            nb += 64;
            xnext = x[min(nb + lane, T_STEPS - 1) * BATCH + b];
        }
        float xvn = bcast_lane(xbuf, tmn);
        float axn = fmaf(xvn, w1xa, b1a);
        float bxn = fmaf(xvn, w1xb, b1b);

        // ---- lgkm-only barrier (4 waves): stores/x-loads stay in flight ----
        asm volatile("s_waitcnt lgkmcnt(0)\n\ts_barrier" ::: "memory");

        float4 d = *(const float4*)&dyx[t & 1][0];   // one broadcast b128
        y += ((d.x + d.y) + (d.z + d.w)) + b3v;      // DT = 1.0

        ybuf = (lane == tm) ? y : ybuf;              // all waves (symmetric)
        if (w == 0 && tm == 63)
            out[(t - 62 + lane) * BATCH + b] = ybuf;

        ax = axn; bx = bxn;
    }
    // tail: t=8128..8190 captured y_8129..y_8191 in lanes 0..62
    if (w == 0 && lane < 63)
        out[(T_STEPS - 63 + lane) * BATCH + b] = ybuf;
}

extern "C" void kernel_launch(void* const* d_in, const int* in_sizes, int n_in,
                              void* d_out, int out_size, void* d_ws, size_t ws_size,
                              hipStream_t stream) {
    const float* x  = (const float*)d_in[0];
    const float* W1 = (const float*)d_in[1];
    const float* b1 = (const float*)d_in[2];
    const float* W2 = (const float*)d_in[3];
    const float* b2 = (const float*)d_in[4];
    const float* W3 = (const float*)d_in[5];
    const float* b3 = (const float*)d_in[6];

    odenet_scan<<<dim3(BATCH), dim3(NTHR), 0, stream>>>(
        x, W1, b1, W2, b2, W3, b3, (float*)d_out);
}